// Round 7
// baseline (1080.152 us; speedup 1.0000x reference)
//
#include <hip/hip_runtime.h>
#include <math.h>

// Problem constants
#define NB    64     // batch
#define NQn   256    // queries
#define NNn   512    // nodes
#define HDn   128    // H*D = EMB
#define LOG2E 1.44269504088896340736f
#define INV_SQRT_EMB 0.08838834764831845f   // 1/sqrt(128)

__device__ __forceinline__ float4 ldg4(const float* p) {
    return *reinterpret_cast<const float4*>(p);
}

// ---------------------------------------------------------------------------
// mask_transpose: mask[b][q][n] (f32, 0 / -inf) -> maskT8[b][n][q] (u8, 0/1).
// ---------------------------------------------------------------------------
__global__ __launch_bounds__(256, 4)
void mask_transpose(const float* __restrict__ mask, unsigned char* __restrict__ maskT8)
{
    const int tid = threadIdx.x;
    const int w   = tid >> 6;                       // q-subgroup of 16
    const int n   = blockIdx.z * 64 + (tid & 63);
    const int b   = blockIdx.x;
    const int q0  = blockIdx.y * 64 + w * 16;
    unsigned int u[4] = {0u, 0u, 0u, 0u};
    #pragma unroll
    for (int j = 0; j < 16; ++j) {
        float v = mask[((size_t)(b * NQn + q0 + j)) * NNn + n];
        unsigned int bit = (v != 0.0f) ? 1u : 0u;   // mask is exactly 0 or -inf
        u[j >> 2] |= bit << (8 * (j & 3));
    }
    *reinterpret_cast<uint4*>(maskT8 + ((size_t)(b * NNn + n)) * NQn + q0) =
        make_uint4(u[0], u[1], u[2], u[3]);
}

// ---------------------------------------------------------------------------
// proj_kernel (proven R3 version): Y[R x 128] = X[R x 128] @ W[128 x 128]
// (+ attr*wrow rank-1, + bias). grid (R/64, 2 col-halves), block 256 (4 waves),
// 2 blocks/CU. 4x4 acc/thread. Optional second pass reuses the staged X tile.
// ---------------------------------------------------------------------------
__global__ __launch_bounds__(256, 2)
void proj_kernel(const float* __restrict__ X,
                 const float* __restrict__ W0, const float* __restrict__ W1,
                 const float* __restrict__ wrow, const float* __restrict__ attr,
                 const float* __restrict__ bias,
                 float* __restrict__ Y0, float* __restrict__ Y1)
{
    __shared__ float Xs[64 * 128];
    __shared__ float Wt[64 * 128];
    const int tid = threadIdx.x;
    const int rg = tid >> 4;          // 0..15
    const int cg = tid & 15;          // 0..15
    const int rowblk = blockIdx.x * 64;
    const int colbase = blockIdx.y * 64;

    #pragma unroll
    for (int i = 0; i < 8; ++i) {
        int idx = tid + 256 * i;      // f4 index in [0,2048)
        int r = idx >> 5;             // 32 f4 per row
        int c4 = idx & 31;
        float4 v = ldg4(X + (rowblk + r) * 128 + c4 * 4);
        *reinterpret_cast<float4*>(&Xs[r * 128 + ((c4 ^ (r & 7)) << 2)]) = v;
    }

    for (int pass = 0; pass < 2; ++pass) {
        if (pass && (W1 == nullptr)) break;
        const float* W = pass ? W1 : W0;
        float* Y = pass ? Y1 : Y0;
        __syncthreads();
        #pragma unroll
        for (int i = 0; i < 32; ++i) {
            int idx = tid + 256 * i;  // 8192 scalars
            int k = idx >> 6;         // 0..127
            int c = idx & 63;         // 0..63
            float w = W[k * 128 + colbase + c];
            Wt[c * 128 + ((((k >> 2) ^ (c & 7)) << 2) | (k & 3))] = w;
        }
        __syncthreads();

        float acc[4][4];
        #pragma unroll
        for (int r = 0; r < 4; ++r)
            #pragma unroll
            for (int c = 0; c < 4; ++c) acc[r][c] = 0.f;

        const int rsw = rg & 7;
        const int csw = cg & 7;
        #pragma unroll 8
        for (int k4 = 0; k4 < 32; ++k4) {
            float4 a[4], bv[4];
            #pragma unroll
            for (int r = 0; r < 4; ++r)
                a[r] = *reinterpret_cast<const float4*>(&Xs[(rg + 16 * r) * 128 + ((k4 ^ rsw) << 2)]);
            #pragma unroll
            for (int c = 0; c < 4; ++c)
                bv[c] = *reinterpret_cast<const float4*>(&Wt[(cg + 16 * c) * 128 + ((k4 ^ csw) << 2)]);
            #pragma unroll
            for (int r = 0; r < 4; ++r)
                #pragma unroll
                for (int c = 0; c < 4; ++c)
                    acc[r][c] += a[r].x * bv[c].x + a[r].y * bv[c].y
                               + a[r].z * bv[c].z + a[r].w * bv[c].w;
        }

        if (attr != nullptr) {
            #pragma unroll
            for (int r = 0; r < 4; ++r) {
                float av = attr[rowblk + rg + 16 * r];
                #pragma unroll
                for (int c = 0; c < 4; ++c)
                    acc[r][c] += av * wrow[colbase + cg + 16 * c];
            }
        }
        #pragma unroll
        for (int r = 0; r < 4; ++r) {
            int row = rowblk + rg + 16 * r;
            #pragma unroll
            for (int c = 0; c < 4; ++c) {
                int col = colbase + cg + 16 * c;
                float o = acc[r][c];
                if (bias != nullptr) o += bias[col];
                Y[row * 128 + col] = o;
            }
        }
    }
}

// ---------------------------------------------------------------------------
// attn_kernel v7: in-block node-split, NO global partials, NO hot-loop barrier.
// grid (64 b, 8 h) = 512 blocks x 512 thr -> 2 blocks/CU = 4 waves/SIMD
// (breaks v5's 2048-wave = 2/SIMD invariant; total waves now 4096).
// Wave w owns nodes w*64..+63 for head h: stages its K/V fragments into a
// PRIVATE 8KB LDS region (reg-staged; own-wave visibility needs only lgkmcnt,
// compiler-inserted -> no __syncthreads until the merge). 4 q-rows per lane
// (q=4*lane+qq) amortize each broadcast ds_read_b128 over 4 dot/PV pairs.
// Mask: 1 coalesced u32 (4 q bytes) per (node,lane) from transposed u8 tensor.
// Fixed-shift softmax (validated r1-r5): p = exp2(dot*0.25*log2e), mask->0.
// Epilogue: 3-round LDS merge tree ([slot][lane] layout, conflict-free),
// wave 0 normalizes and writes final ATT (l==0 rows -> V[b][node0] slice).
// ---------------------------------------------------------------------------
__global__ __launch_bounds__(512, 4)
void attn_kernel(const float* __restrict__ Q, const float* __restrict__ K,
                 const float* __restrict__ V, const unsigned int* __restrict__ maskTu,
                 float* __restrict__ ATT)
{
    __shared__ float lds[16384];      // 64KB: stage [8 waves][2048] / merge 3x4352
    const int tid  = threadIdx.x;
    const int lane = tid & 63;
    const int w    = tid >> 6;        // wave = node-split 0..7
    const int b    = blockIdx.x;
    const int h    = blockIdx.y;

    float* Wr = &lds[w * 2048];       // wave region: K [64][16] at 0, V at +1024

    // --- stage this wave's 64 nodes (reg-staged, coalesced, no barrier) ---
    {
        const int nl = lane >> 2;             // node within 16-group
        const int ch = (lane & 3) * 4;        // float chunk
        const size_t gbase = (size_t)(b * NNn + w * 64 + nl) * 128 + h * 16 + ch;
        #pragma unroll
        for (int i = 0; i < 4; ++i) {
            float4 kv = ldg4(K + gbase + (size_t)i * 16 * 128);
            *reinterpret_cast<float4*>(&Wr[i * 256 + (nl * 16 + ch)]) = kv;
        }
        #pragma unroll
        for (int i = 0; i < 4; ++i) {
            float4 vv = ldg4(V + gbase + (size_t)i * 16 * 128);
            *reinterpret_cast<float4*>(&Wr[1024 + i * 256 + (nl * 16 + ch)]) = vv;
        }
    }

    // --- q fragments, pre-scaled by 0.25*log2e ---
    float qv[4][16];
    {
        const float sc = 0.25f * LOG2E;
        #pragma unroll
        for (int qq = 0; qq < 4; ++qq) {
            const float* qp = Q + ((size_t)(b * NQn + 4 * lane + qq)) * 128 + h * 16;
            #pragma unroll
            for (int j = 0; j < 4; ++j) {
                float4 tv = ldg4(qp + 4 * j);
                qv[qq][4*j+0] = tv.x * sc; qv[qq][4*j+1] = tv.y * sc;
                qv[qq][4*j+2] = tv.z * sc; qv[qq][4*j+3] = tv.w * sc;
            }
        }
    }

    float out[4][16];
    #pragma unroll
    for (int qq = 0; qq < 4; ++qq)
        #pragma unroll
        for (int d = 0; d < 16; ++d) out[qq][d] = 0.f;
    float ls[4] = {0.f, 0.f, 0.f, 0.f};

    const unsigned int* mb = maskTu + ((size_t)(b * NNn + w * 64)) * 64 + lane;

    // --- hot loop: 64 nodes, broadcast LDS reads, no barriers ---
    #pragma unroll 8
    for (int n = 0; n < 64; ++n) {
        float kf[16], vf[16];
        *reinterpret_cast<float4*>(&kf[0])  = *reinterpret_cast<const float4*>(&Wr[n*16]);
        *reinterpret_cast<float4*>(&kf[4])  = *reinterpret_cast<const float4*>(&Wr[n*16+4]);
        *reinterpret_cast<float4*>(&kf[8])  = *reinterpret_cast<const float4*>(&Wr[n*16+8]);
        *reinterpret_cast<float4*>(&kf[12]) = *reinterpret_cast<const float4*>(&Wr[n*16+12]);
        *reinterpret_cast<float4*>(&vf[0])  = *reinterpret_cast<const float4*>(&Wr[1024+n*16]);
        *reinterpret_cast<float4*>(&vf[4])  = *reinterpret_cast<const float4*>(&Wr[1024+n*16+4]);
        *reinterpret_cast<float4*>(&vf[8])  = *reinterpret_cast<const float4*>(&Wr[1024+n*16+8]);
        *reinterpret_cast<float4*>(&vf[12]) = *reinterpret_cast<const float4*>(&Wr[1024+n*16+12]);
        unsigned int m4 = mb[(size_t)n * 64];

        float p[4];
        #pragma unroll
        for (int qq = 0; qq < 4; ++qq) {
            float aP = qv[qq][0]*kf[0] + qv[qq][1]*kf[1] + qv[qq][2]*kf[2] + qv[qq][3]*kf[3];
            float aQ = qv[qq][4]*kf[4] + qv[qq][5]*kf[5] + qv[qq][6]*kf[6] + qv[qq][7]*kf[7];
            float aR = qv[qq][8]*kf[8] + qv[qq][9]*kf[9] + qv[qq][10]*kf[10] + qv[qq][11]*kf[11];
            float aS = qv[qq][12]*kf[12] + qv[qq][13]*kf[13] + qv[qq][14]*kf[14] + qv[qq][15]*kf[15];
            p[qq] = exp2f((aP + aQ) + (aR + aS));
        }
        p[0] = (m4 & 0x000000ffu) ? 0.f : p[0];
        p[1] = (m4 & 0x0000ff00u) ? 0.f : p[1];
        p[2] = (m4 & 0x00ff0000u) ? 0.f : p[2];
        p[3] = (m4 & 0xff000000u) ? 0.f : p[3];
        ls[0] += p[0]; ls[1] += p[1]; ls[2] += p[2]; ls[3] += p[3];
        #pragma unroll
        for (int d = 0; d < 16; ++d) {
            out[0][d] += p[0] * vf[d];
            out[1][d] += p[1] * vf[d];
            out[2][d] += p[2] * vf[d];
            out[3][d] += p[3] * vf[d];
        }
    }

    // --- merge tree: [slot][lane] layout (68 slots x 64 lanes per region) ---
    float* R0 = lds;
    float* R1 = lds + 4352;
    float* R2 = lds + 8704;
    #define MERGE_WRITE(R)                                                     \
        { float* s_ = (R);                                                     \
          _Pragma("unroll")                                                    \
          for (int qq = 0; qq < 4; ++qq) {                                     \
              _Pragma("unroll")                                                \
              for (int d = 0; d < 16; ++d) s_[(qq*17+d)*64 + lane] = out[qq][d]; \
              s_[(qq*17+16)*64 + lane] = ls[qq]; } }
    #define MERGE_READ(R)                                                      \
        { const float* s_ = (R);                                               \
          _Pragma("unroll")                                                    \
          for (int qq = 0; qq < 4; ++qq) {                                     \
              _Pragma("unroll")                                                \
              for (int d = 0; d < 16; ++d) out[qq][d] += s_[(qq*17+d)*64 + lane]; \
              ls[qq] += s_[(qq*17+16)*64 + lane]; } }

    __syncthreads();                           // all waves done with stage regions
    if (w == 1) MERGE_WRITE(R0)
    if (w == 3) MERGE_WRITE(R1)
    if (w == 5) MERGE_WRITE(R2)
    __syncthreads();
    if (w == 0) MERGE_READ(R0)                 // 0+1
    if (w == 2) MERGE_READ(R1)                 // 2+3
    if (w == 4) MERGE_READ(R2)                 // 4+5
    __syncthreads();
    if (w == 2) MERGE_WRITE(R0)
    if (w == 6) MERGE_WRITE(R1)
    if (w == 7) MERGE_WRITE(R2)
    __syncthreads();
    if (w == 0) MERGE_READ(R0)                 // 0..3
    if (w == 4) { MERGE_READ(R1) MERGE_READ(R2) }  // 4..7
    __syncthreads();
    if (w == 4) MERGE_WRITE(R0)
    __syncthreads();
    if (w == 0) {
        MERGE_READ(R0)                         // 0..7 complete
        #pragma unroll
        for (int qq = 0; qq < 4; ++qq) {
            float l = ls[qq];
            float rinv = __builtin_amdgcn_rcpf(l);
            if (l == 0.0f) {                   // fully-masked row -> node 0 one-hot
                const float* v0 = V + ((size_t)b * NNn) * 128 + h * 16;
                #pragma unroll
                for (int d = 0; d < 16; ++d) out[qq][d] = v0[d];
                rinv = 1.0f;
            }
            float* op = ATT + ((size_t)(b * NQn + 4 * lane + qq)) * 128 + h * 16;
            *reinterpret_cast<float4*>(op)      = make_float4(out[qq][0]*rinv,  out[qq][1]*rinv,  out[qq][2]*rinv,  out[qq][3]*rinv);
            *reinterpret_cast<float4*>(op + 4)  = make_float4(out[qq][4]*rinv,  out[qq][5]*rinv,  out[qq][6]*rinv,  out[qq][7]*rinv);
            *reinterpret_cast<float4*>(op + 8)  = make_float4(out[qq][8]*rinv,  out[qq][9]*rinv,  out[qq][10]*rinv, out[qq][11]*rinv);
            *reinterpret_cast<float4*>(op + 12) = make_float4(out[qq][12]*rinv, out[qq][13]*rinv, out[qq][14]*rinv, out[qq][15]*rinv);
        }
    }
    #undef MERGE_WRITE
    #undef MERGE_READ
}

// ---------------------------------------------------------------------------
// final_kernel (R4-v2, proven): probs = softmax(10*tanh(MH@EN^T/sqrt128)+mask).
// q-tile 32 -> grid 512 = 2 blocks/CU. Block 512 thr: 1 q-row per thread,
// EN m-tiles of 128 in 64KB swizzled LDS; fixed softmax shift; pr[32] static.
// ---------------------------------------------------------------------------
__global__ __launch_bounds__(512, 4)
void final_kernel(const float* __restrict__ MH, const float* __restrict__ EN,
                  const float* __restrict__ mask, float* __restrict__ OUT)
{
    __shared__ float ENs[128 * 128];
    const int tid = threadIdx.x;
    const int qg = tid >> 4;          // 0..31 (1 q-row each)
    const int mg = tid & 15;          // 0..15 (m = mg + 16c)
    const int b  = blockIdx.x >> 3;
    const int q0 = (blockIdx.x & 7) * 32;

    const float* mhrow = MH + (b * NQn + q0 + qg) * 128;
    float pr[32];
    float psum = 0.f;
    const int msw = mg & 7;

    #pragma unroll
    for (int t = 0; t < 4; ++t) {
        const int m0 = t * 128;
        __syncthreads();
        #pragma unroll
        for (int i = 0; i < 8; ++i) {
            int idx = tid + 512 * i;
            int r = idx >> 5;
            int c4 = idx & 31;
            float4 v = ldg4(EN + (b * NNn + m0 + r) * 128 + c4 * 4);
            *reinterpret_cast<float4*>(&ENs[r * 128 + ((c4 ^ (r & 7)) << 2)]) = v;
        }
        __syncthreads();

        float acc[8];
        #pragma unroll
        for (int c = 0; c < 8; ++c) acc[c] = 0.f;

        #pragma unroll 4
        for (int k4 = 0; k4 < 32; ++k4) {
            float4 a0 = ldg4(mhrow + k4 * 4);      // L1-resident, 16-lane broadcast
            float4 bv[8];
            #pragma unroll
            for (int c = 0; c < 8; ++c)
                bv[c] = *reinterpret_cast<const float4*>(&ENs[(mg + 16 * c) * 128 + ((k4 ^ msw) << 2)]);
            #pragma unroll
            for (int c = 0; c < 8; ++c)
                acc[c] += a0.x*bv[c].x + a0.y*bv[c].y + a0.z*bv[c].z + a0.w*bv[c].w;
        }

        const float* mrow = mask + (b * NQn + q0 + qg) * NNn + m0;
        #pragma unroll
        for (int c = 0; c < 8; ++c) {
            int m = mg + 16 * c;
            float s2 = acc[c] * INV_SQRT_EMB;
            float e  = exp2f(s2 * (2.0f * LOG2E));
            float rc = __builtin_amdgcn_rcpf(e + 1.0f);
            float mv = mrow[m];
            float pv = exp2f((mv - 20.0f * rc) * LOG2E);
            pr[t * 8 + c] = pv;
            psum += pv;
        }
    }

    {
        float s = psum;
        s += __shfl_xor(s, 1);
        s += __shfl_xor(s, 2);
        s += __shfl_xor(s, 4);
        s += __shfl_xor(s, 8);
        psum = s;
    }

    float* orow = OUT + (b * NQn + q0 + qg) * NNn;
    if (psum == 0.0f) {
        #pragma unroll
        for (int t = 0; t < 4; ++t)
            #pragma unroll
            for (int c = 0; c < 8; ++c) {
                int m = t * 128 + mg + 16 * c;
                orow[m] = (m == 0) ? 1.0f : 0.0f;
            }
    } else {
        float inv = __builtin_amdgcn_rcpf(psum);
        #pragma unroll
        for (int t = 0; t < 4; ++t)
            #pragma unroll
            for (int c = 0; c < 8; ++c)
                orow[t * 128 + mg + 16 * c] = pr[t * 8 + c] * inv;
    }
}

// ---------------------------------------------------------------------------
extern "C" void kernel_launch(void* const* d_in, const int* in_sizes, int n_in,
                              void* d_out, int out_size, void* d_ws, size_t ws_size,
                              hipStream_t stream) {
    const float* enc_last  = (const float*)d_in[0];   // [B,NQ,128]
    const float* attr      = (const float*)d_in[1];   // [B,NQ,1]
    const float* enc_nodes = (const float*)d_in[2];   // [B,NN,128]
    const float* mask      = (const float*)d_in[3];   // [B,NQ,NN]
    const float* Wq        = (const float*)d_in[4];   // [129,128]
    const float* Wk        = (const float*)d_in[5];   // [128,128]
    const float* Wv        = (const float*)d_in[6];   // [128,128]
    const float* Wcomb     = (const float*)d_in[7];   // [128,128]
    const float* bcomb     = (const float*)d_in[8];   // [128]
    float* out = (float*)d_out;

    float* Kbuf = (float*)d_ws;                         // [B*NN,128] 16.8MB
    float* Vbuf = Kbuf + (size_t)NB * NNn * 128;        // [B*NN,128] 16.8MB
    float* Qbuf = Vbuf + (size_t)NB * NNn * 128;        // [B*NQ,128]  8.4MB
    float* ATT  = Qbuf + (size_t)NB * NQn * 128;        // [B*NQ,128]  8.4MB
    float* MH   = ATT  + (size_t)NB * NQn * 128;        // [B*NQ,128]  8.4MB
    unsigned char* maskT8 = (unsigned char*)(MH + (size_t)NB * NQn * 128);  // 8.4MB

    // mask -> transposed u8 [b][n][q]
    mask_transpose<<<dim3(NB, NQn / 64, NNn / 64), 256, 0, stream>>>(mask, maskT8);
    // K,V projections (dual-pass over shared X tile)
    proj_kernel<<<dim3(NB * NNn / 64, 2), 256, 0, stream>>>(
        enc_nodes, Wk, Wv, nullptr, nullptr, nullptr, Kbuf, Vbuf);
    // Q projection (concat attr handled as rank-1 term with Wq row 128)
    proj_kernel<<<dim3(NB * NQn / 64, 2), 256, 0, stream>>>(
        enc_last, Wq, nullptr, Wq + 128 * 128, attr, nullptr, Qbuf, nullptr);
    // masked multi-head attention, in-block node-split + LDS merge
    attn_kernel<<<dim3(NB, 8), 512, 0, stream>>>(
        Qbuf, Kbuf, Vbuf, (const unsigned int*)maskT8, ATT);
    // combine projection + bias
    proj_kernel<<<dim3(NB * NQn / 64, 2), 256, 0, stream>>>(
        ATT, Wcomb, nullptr, nullptr, nullptr, bcomb, MH, nullptr);
    // compatibility score + tanh clip + masked softmax
    final_kernel<<<dim3(NB * NQn / 32), 512, 0, stream>>>(
        MH, enc_nodes, mask, out);
}

// Round 8
// 266.383 us; speedup vs baseline: 4.0549x; 4.0549x over previous
//
#include <hip/hip_runtime.h>
#include <math.h>

// Problem constants
#define NB    64     // batch
#define NQn   256    // queries
#define NNn   512    // nodes
#define HDn   128    // H*D = EMB
#define LOG2E 1.44269504088896340736f
#define INV_SQRT_EMB 0.08838834764831845f   // 1/sqrt(128)

__device__ __forceinline__ float4 ldg4(const float* p) {
    return *reinterpret_cast<const float4*>(p);
}

// ---------------------------------------------------------------------------
// mask_transpose: mask[b][q][n] (f32, 0 / -inf) -> maskT8[b][n][q] (u8, 0/1).
// ---------------------------------------------------------------------------
__global__ __launch_bounds__(256, 4)
void mask_transpose(const float* __restrict__ mask, unsigned char* __restrict__ maskT8)
{
    const int tid = threadIdx.x;
    const int w   = tid >> 6;                       // q-subgroup of 16
    const int n   = blockIdx.z * 64 + (tid & 63);
    const int b   = blockIdx.x;
    const int q0  = blockIdx.y * 64 + w * 16;
    unsigned int u[4] = {0u, 0u, 0u, 0u};
    #pragma unroll
    for (int j = 0; j < 16; ++j) {
        float v = mask[((size_t)(b * NQn + q0 + j)) * NNn + n];
        unsigned int bit = (v != 0.0f) ? 1u : 0u;   // mask is exactly 0 or -inf
        u[j >> 2] |= bit << (8 * (j & 3));
    }
    *reinterpret_cast<uint4*>(maskT8 + ((size_t)(b * NNn + n)) * NQn + q0) =
        make_uint4(u[0], u[1], u[2], u[3]);
}

// ---------------------------------------------------------------------------
// proj_kernel (proven R3): Y[R x 128] = X[R x 128] @ W[128 x 128]
// (+ attr*wrow rank-1, + bias). grid (R/64, 2 col-halves), block 256 (4 waves).
// Optional second pass reuses the staged X tile (used for K and V).
// ---------------------------------------------------------------------------
__global__ __launch_bounds__(256, 2)
void proj_kernel(const float* __restrict__ X,
                 const float* __restrict__ W0, const float* __restrict__ W1,
                 const float* __restrict__ wrow, const float* __restrict__ attr,
                 const float* __restrict__ bias,
                 float* __restrict__ Y0, float* __restrict__ Y1)
{
    __shared__ float Xs[64 * 128];
    __shared__ float Wt[64 * 128];
    const int tid = threadIdx.x;
    const int rg = tid >> 4;          // 0..15
    const int cg = tid & 15;          // 0..15
    const int rowblk = blockIdx.x * 64;
    const int colbase = blockIdx.y * 64;

    #pragma unroll
    for (int i = 0; i < 8; ++i) {
        int idx = tid + 256 * i;      // f4 index in [0,2048)
        int r = idx >> 5;             // 32 f4 per row
        int c4 = idx & 31;
        float4 v = ldg4(X + (rowblk + r) * 128 + c4 * 4);
        *reinterpret_cast<float4*>(&Xs[r * 128 + ((c4 ^ (r & 7)) << 2)]) = v;
    }

    for (int pass = 0; pass < 2; ++pass) {
        if (pass && (W1 == nullptr)) break;
        const float* W = pass ? W1 : W0;
        float* Y = pass ? Y1 : Y0;
        __syncthreads();
        #pragma unroll
        for (int i = 0; i < 32; ++i) {
            int idx = tid + 256 * i;  // 8192 scalars
            int k = idx >> 6;         // 0..127
            int c = idx & 63;         // 0..63
            float w = W[k * 128 + colbase + c];
            Wt[c * 128 + ((((k >> 2) ^ (c & 7)) << 2) | (k & 3))] = w;
        }
        __syncthreads();

        float acc[4][4];
        #pragma unroll
        for (int r = 0; r < 4; ++r)
            #pragma unroll
            for (int c = 0; c < 4; ++c) acc[r][c] = 0.f;

        const int rsw = rg & 7;
        const int csw = cg & 7;
        #pragma unroll 8
        for (int k4 = 0; k4 < 32; ++k4) {
            float4 a[4], bv[4];
            #pragma unroll
            for (int r = 0; r < 4; ++r)
                a[r] = *reinterpret_cast<const float4*>(&Xs[(rg + 16 * r) * 128 + ((k4 ^ rsw) << 2)]);
            #pragma unroll
            for (int c = 0; c < 4; ++c)
                bv[c] = *reinterpret_cast<const float4*>(&Wt[(cg + 16 * c) * 128 + ((k4 ^ csw) << 2)]);
            #pragma unroll
            for (int r = 0; r < 4; ++r)
                #pragma unroll
                for (int c = 0; c < 4; ++c)
                    acc[r][c] += a[r].x * bv[c].x + a[r].y * bv[c].y
                               + a[r].z * bv[c].z + a[r].w * bv[c].w;
        }

        if (attr != nullptr) {
            #pragma unroll
            for (int r = 0; r < 4; ++r) {
                float av = attr[rowblk + rg + 16 * r];
                #pragma unroll
                for (int c = 0; c < 4; ++c)
                    acc[r][c] += av * wrow[colbase + cg + 16 * c];
            }
        }
        #pragma unroll
        for (int r = 0; r < 4; ++r) {
            int row = rowblk + rg + 16 * r;
            #pragma unroll
            for (int c = 0; c < 4; ++c) {
                int col = colbase + cg + 16 * c;
                float o = acc[r][c];
                if (bias != nullptr) o += bias[col];
                Y[row * 128 + col] = o;
            }
        }
    }
}

// ---------------------------------------------------------------------------
// attn_kernel v8: 2 q-rows/lane -> 2x LDS-broadcast reuse AND <=128 VGPRs,
// so __launch_bounds__(512,4) holds WITHOUT spilling (v7 post-mortem: 4q/lane
// state ~160 regs under a 128 cap -> 4.6GB scratch traffic; 2q/lane ~100 regs).
// Block 512 = 8 waves = 8 heads, lanes cover 128 q (q = qt*128 + 2*lane + qq);
// grid (64 b, 2 qt, 4 ns) = 512 blocks -> 2 blocks/CU = 4 waves/SIMD.
// K staged then V staged per 32-node tile (shared across the 8 heads);
// hot loop phases K-dots before V-loads so peak live regs stay low.
// Mask: 1 coalesced u16 (2 q bytes) per (node,lane) from transposed tensor.
// Fixed-shift softmax (validated r1-r7): p = exp2(dot*0.25*log2e), mask->0.
// Partials linear -> attn_merge.
// ---------------------------------------------------------------------------
__global__ __launch_bounds__(512, 4)
void attn_kernel(const float* __restrict__ Q, const float* __restrict__ K,
                 const float* __restrict__ V, const unsigned char* __restrict__ maskT8,
                 float* __restrict__ P0, float* __restrict__ P1,
                 float* __restrict__ P2, float* __restrict__ P3,
                 float* __restrict__ L0, float* __restrict__ L1,
                 float* __restrict__ L2, float* __restrict__ L3)
{
    __shared__ float Ks[32 * 128];    // 16KB
    __shared__ float Vs[32 * 128];    // 16KB
    const int tid  = threadIdx.x;
    const int lane = tid & 63;
    const int h    = tid >> 6;        // wave = head
    const int b    = blockIdx.x;
    const int qt   = blockIdx.y;      // q half
    const int ns   = blockIdx.z;      // node split 0..3
    const int q0   = qt * 128 + 2 * lane;
    const int nbase = ns * 128;

    // 2 q fragments, pre-scaled by 0.25*log2e
    float qv[2][16];
    {
        const float sc = 0.25f * LOG2E;
        #pragma unroll
        for (int qq = 0; qq < 2; ++qq) {
            const float* qp = Q + ((size_t)(b * NQn + q0 + qq)) * 128 + h * 16;
            #pragma unroll
            for (int j = 0; j < 4; ++j) {
                float4 tv = ldg4(qp + 4 * j);
                qv[qq][4*j+0] = tv.x * sc; qv[qq][4*j+1] = tv.y * sc;
                qv[qq][4*j+2] = tv.z * sc; qv[qq][4*j+3] = tv.w * sc;
            }
        }
    }

    float out[2][16];
    #pragma unroll
    for (int qq = 0; qq < 2; ++qq)
        #pragma unroll
        for (int d = 0; d < 16; ++d) out[qq][d] = 0.f;
    float ls0 = 0.f, ls1 = 0.f;

    // per-node mask u16 (2 q bytes) for this lane; node stride = 128 ushorts
    const unsigned short* mb = reinterpret_cast<const unsigned short*>(
        maskT8 + ((size_t)(b * NNn + nbase)) * NQn + q0);

    for (int t = 0; t < 4; ++t) {
        __syncthreads();
        {   // stage 32-node K/V tile: 2 f4/thread each, coalesced, linear
            const float* kg = K + ((size_t)(b * NNn + nbase + t * 32)) * 128;
            const float* vg = V + ((size_t)(b * NNn + nbase + t * 32)) * 128;
            float4 k0 = ldg4(kg + tid * 4);
            float4 k1 = ldg4(kg + (tid + 512) * 4);
            *reinterpret_cast<float4*>(&Ks[tid * 4]) = k0;
            *reinterpret_cast<float4*>(&Ks[(tid + 512) * 4]) = k1;
            float4 v0 = ldg4(vg + tid * 4);
            float4 v1 = ldg4(vg + (tid + 512) * 4);
            *reinterpret_cast<float4*>(&Vs[tid * 4]) = v0;
            *reinterpret_cast<float4*>(&Vs[(tid + 512) * 4]) = v1;
        }
        __syncthreads();

        const float* kbase = &Ks[h * 16];
        const float* vbase = &Vs[h * 16];
        for (int n = 0; n < 32; ++n) {
            unsigned int m2 = mb[(size_t)(t * 32 + n) * 128];
            // --- K phase (4 float4 live) ---
            float4 k0 = *reinterpret_cast<const float4*>(kbase + n * 128);
            float4 k1 = *reinterpret_cast<const float4*>(kbase + n * 128 + 4);
            float4 k2 = *reinterpret_cast<const float4*>(kbase + n * 128 + 8);
            float4 k3 = *reinterpret_cast<const float4*>(kbase + n * 128 + 12);
            float s0 = (qv[0][0]*k0.x + qv[0][1]*k0.y + qv[0][2]*k0.z + qv[0][3]*k0.w)
                     + (qv[0][4]*k1.x + qv[0][5]*k1.y + qv[0][6]*k1.z + qv[0][7]*k1.w)
                     + (qv[0][8]*k2.x + qv[0][9]*k2.y + qv[0][10]*k2.z + qv[0][11]*k2.w)
                     + (qv[0][12]*k3.x + qv[0][13]*k3.y + qv[0][14]*k3.z + qv[0][15]*k3.w);
            float s1 = (qv[1][0]*k0.x + qv[1][1]*k0.y + qv[1][2]*k0.z + qv[1][3]*k0.w)
                     + (qv[1][4]*k1.x + qv[1][5]*k1.y + qv[1][6]*k1.z + qv[1][7]*k1.w)
                     + (qv[1][8]*k2.x + qv[1][9]*k2.y + qv[1][10]*k2.z + qv[1][11]*k2.w)
                     + (qv[1][12]*k3.x + qv[1][13]*k3.y + qv[1][14]*k3.z + qv[1][15]*k3.w);
            float p0 = (m2 & 0x00ffu) ? 0.f : exp2f(s0);
            float p1 = (m2 & 0xff00u) ? 0.f : exp2f(s1);
            ls0 += p0; ls1 += p1;
            // --- V phase (K regs reused) ---
            float4 v0 = *reinterpret_cast<const float4*>(vbase + n * 128);
            float4 v1 = *reinterpret_cast<const float4*>(vbase + n * 128 + 4);
            float4 v2 = *reinterpret_cast<const float4*>(vbase + n * 128 + 8);
            float4 v3 = *reinterpret_cast<const float4*>(vbase + n * 128 + 12);
            out[0][0]  += p0*v0.x; out[0][1]  += p0*v0.y; out[0][2]  += p0*v0.z; out[0][3]  += p0*v0.w;
            out[0][4]  += p0*v1.x; out[0][5]  += p0*v1.y; out[0][6]  += p0*v1.z; out[0][7]  += p0*v1.w;
            out[0][8]  += p0*v2.x; out[0][9]  += p0*v2.y; out[0][10] += p0*v2.z; out[0][11] += p0*v2.w;
            out[0][12] += p0*v3.x; out[0][13] += p0*v3.y; out[0][14] += p0*v3.z; out[0][15] += p0*v3.w;
            out[1][0]  += p1*v0.x; out[1][1]  += p1*v0.y; out[1][2]  += p1*v0.z; out[1][3]  += p1*v0.w;
            out[1][4]  += p1*v1.x; out[1][5]  += p1*v1.y; out[1][6]  += p1*v1.z; out[1][7]  += p1*v1.w;
            out[1][8]  += p1*v2.x; out[1][9]  += p1*v2.y; out[1][10] += p1*v2.z; out[1][11] += p1*v2.w;
            out[1][12] += p1*v3.x; out[1][13] += p1*v3.y; out[1][14] += p1*v3.z; out[1][15] += p1*v3.w;
        }
    }

    float* P = (ns == 0) ? P0 : (ns == 1) ? P1 : (ns == 2) ? P2 : P3;
    float* L = (ns == 0) ? L0 : (ns == 1) ? L1 : (ns == 2) ? L2 : L3;
    #pragma unroll
    for (int qq = 0; qq < 2; ++qq) {
        float* op = P + ((size_t)(b * NQn + q0 + qq)) * 128 + h * 16;
        *reinterpret_cast<float4*>(op)      = make_float4(out[qq][0],  out[qq][1],  out[qq][2],  out[qq][3]);
        *reinterpret_cast<float4*>(op + 4)  = make_float4(out[qq][4],  out[qq][5],  out[qq][6],  out[qq][7]);
        *reinterpret_cast<float4*>(op + 8)  = make_float4(out[qq][8],  out[qq][9],  out[qq][10], out[qq][11]);
        *reinterpret_cast<float4*>(op + 12) = make_float4(out[qq][12], out[qq][13], out[qq][14], out[qq][15]);
        L[(b * NQn + q0 + qq) * 8 + h] = (qq == 0) ? ls0 : ls1;
    }
}

// ---------------------------------------------------------------------------
// attn_merge (proven R4): ATT = (P0..P3)/(L0..L3); l==0 rows -> V[b][node0].
// P0 aliases ATT (per-thread read-then-write, safe). grid 2048 x 256.
// ---------------------------------------------------------------------------
__global__ __launch_bounds__(256, 4)
void attn_merge(const float* __restrict__ P0, const float* __restrict__ P1,
                const float* __restrict__ P2, const float* __restrict__ P3,
                const float* __restrict__ L0, const float* __restrict__ L1,
                const float* __restrict__ L2, const float* __restrict__ L3,
                const float* __restrict__ V, float* __restrict__ ATT)
{
    const int idx = blockIdx.x * 256 + threadIdx.x;  // f4 index over B*NQ*32
    const int row = idx >> 5;                        // b*NQ + q
    const int f4i = idx & 31;
    const int hh  = f4i >> 2;
    const int b   = row >> 8;
    const float l = (L0[row * 8 + hh] + L1[row * 8 + hh])
                  + (L2[row * 8 + hh] + L3[row * 8 + hh]);
    float4 a = ldg4(P0 + (size_t)row * 128 + f4i * 4);
    float4 c = ldg4(P1 + (size_t)row * 128 + f4i * 4);
    float4 d = ldg4(P2 + (size_t)row * 128 + f4i * 4);
    float4 e = ldg4(P3 + (size_t)row * 128 + f4i * 4);
    float4 r;
    if (l == 0.0f) {
        r = ldg4(V + (size_t)b * NNn * 128 + f4i * 4);   // node 0, one-hot weights
    } else {
        float inv = __builtin_amdgcn_rcpf(l);
        r = make_float4((a.x + c.x + d.x + e.x) * inv, (a.y + c.y + d.y + e.y) * inv,
                        (a.z + c.z + d.z + e.z) * inv, (a.w + c.w + d.w + e.w) * inv);
    }
    *reinterpret_cast<float4*>(ATT + (size_t)row * 128 + f4i * 4) = r;
}

// ---------------------------------------------------------------------------
// final_kernel (proven R3): probs = softmax(10*tanh(MH@EN^T/sqrt128)+mask).
// ---------------------------------------------------------------------------
__global__ __launch_bounds__(512, 2)
void final_kernel(const float* __restrict__ MH, const float* __restrict__ EN,
                  const float* __restrict__ mask, float* __restrict__ OUT)
{
    __shared__ float ENs[128 * 128];
    const int tid = threadIdx.x;
    const int qg = tid >> 4;          // 0..31 (2 q-rows each)
    const int mg = tid & 15;          // 0..15
    const int b  = blockIdx.x >> 2;
    const int q0 = (blockIdx.x & 3) * 64;

    const float* mhbase = MH + (b * NQn + q0) * 128;
    float pr[2][32];
    float psum[2] = {0.f, 0.f};
    const int msw = mg & 7;

    #pragma unroll
    for (int t = 0; t < 4; ++t) {
        const int m0 = t * 128;
        __syncthreads();
        #pragma unroll
        for (int i = 0; i < 8; ++i) {
            int idx = tid + 512 * i;
            int r = idx >> 5;
            int c4 = idx & 31;
            float4 v = ldg4(EN + (b * NNn + m0 + r) * 128 + c4 * 4);
            *reinterpret_cast<float4*>(&ENs[r * 128 + ((c4 ^ (r & 7)) << 2)]) = v;
        }
        __syncthreads();

        float acc[2][8];
        #pragma unroll
        for (int qq = 0; qq < 2; ++qq)
            #pragma unroll
            for (int c = 0; c < 8; ++c) acc[qq][c] = 0.f;

        #pragma unroll 4
        for (int k4 = 0; k4 < 32; ++k4) {
            float4 a0 = ldg4(mhbase + (qg * 2 + 0) * 128 + k4 * 4);
            float4 a1 = ldg4(mhbase + (qg * 2 + 1) * 128 + k4 * 4);
            float4 bv[8];
            #pragma unroll
            for (int c = 0; c < 8; ++c)
                bv[c] = *reinterpret_cast<const float4*>(&ENs[(mg + 16 * c) * 128 + ((k4 ^ msw) << 2)]);
            #pragma unroll
            for (int c = 0; c < 8; ++c) {
                acc[0][c] += a0.x*bv[c].x + a0.y*bv[c].y + a0.z*bv[c].z + a0.w*bv[c].w;
                acc[1][c] += a1.x*bv[c].x + a1.y*bv[c].y + a1.z*bv[c].z + a1.w*bv[c].w;
            }
        }

        #pragma unroll
        for (int qq = 0; qq < 2; ++qq) {
            const int q = q0 + qg * 2 + qq;
            const float* mrow = mask + (b * NQn + q) * NNn + m0;
            #pragma unroll
            for (int c = 0; c < 8; ++c) {
                int m = mg + 16 * c;
                float s2 = acc[qq][c] * INV_SQRT_EMB;
                float e  = exp2f(s2 * (2.0f * LOG2E));
                float rc = __builtin_amdgcn_rcpf(e + 1.0f);
                float mv = mrow[m];
                float pv = exp2f((mv - 20.0f * rc) * LOG2E);
                pr[qq][t * 8 + c] = pv;
                psum[qq] += pv;
            }
        }
    }

    #pragma unroll
    for (int qq = 0; qq < 2; ++qq) {
        float s = psum[qq];
        s += __shfl_xor(s, 1);
        s += __shfl_xor(s, 2);
        s += __shfl_xor(s, 4);
        s += __shfl_xor(s, 8);
        psum[qq] = s;
    }

    #pragma unroll
    for (int qq = 0; qq < 2; ++qq) {
        const int q = q0 + qg * 2 + qq;
        float* orow = OUT + (b * NQn + q) * NNn;
        if (psum[qq] == 0.0f) {
            #pragma unroll
            for (int t = 0; t < 4; ++t)
                #pragma unroll
                for (int c = 0; c < 8; ++c) {
                    int m = t * 128 + mg + 16 * c;
                    orow[m] = (m == 0) ? 1.0f : 0.0f;
                }
        } else {
            float inv = __builtin_amdgcn_rcpf(psum[qq]);
            #pragma unroll
            for (int t = 0; t < 4; ++t)
                #pragma unroll
                for (int c = 0; c < 8; ++c)
                    orow[t * 128 + mg + 16 * c] = pr[qq][t * 8 + c] * inv;
        }
    }
}

// ---------------------------------------------------------------------------
extern "C" void kernel_launch(void* const* d_in, const int* in_sizes, int n_in,
                              void* d_out, int out_size, void* d_ws, size_t ws_size,
                              hipStream_t stream) {
    const float* enc_last  = (const float*)d_in[0];   // [B,NQ,128]
    const float* attr      = (const float*)d_in[1];   // [B,NQ,1]
    const float* enc_nodes = (const float*)d_in[2];   // [B,NN,128]
    const float* mask      = (const float*)d_in[3];   // [B,NQ,NN]
    const float* Wq        = (const float*)d_in[4];   // [129,128]
    const float* Wk        = (const float*)d_in[5];   // [128,128]
    const float* Wv        = (const float*)d_in[6];   // [128,128]
    const float* Wcomb     = (const float*)d_in[7];   // [128,128]
    const float* bcomb     = (const float*)d_in[8];   // [128]
    float* out = (float*)d_out;

    float* Kbuf = (float*)d_ws;                         // [B*NN,128] 16.8MB
    float* Vbuf = Kbuf + (size_t)NB * NNn * 128;        // [B*NN,128] 16.8MB
    float* Qbuf = Vbuf + (size_t)NB * NNn * 128;        // [B*NQ,128]  8.4MB
    float* ATT  = Qbuf + (size_t)NB * NQn * 128;        // 8.4MB (= P0)
    float* P1   = ATT  + (size_t)NB * NQn * 128;        // 8.4MB
    float* P2   = P1   + (size_t)NB * NQn * 128;        // 8.4MB
    float* P3   = P2   + (size_t)NB * NQn * 128;        // 8.4MB
    float* L0   = P3   + (size_t)NB * NQn * 128;        // 0.5MB
    float* L1   = L0   + (size_t)NB * NQn * 8;
    float* L2   = L1   + (size_t)NB * NQn * 8;
    float* L3   = L2   + (size_t)NB * NQn * 8;
    unsigned char* maskT8 = (unsigned char*)(L3 + (size_t)NB * NQn * 8);  // 8.4MB
    float* MH   = Qbuf;   // alias: Qbuf dead after attn; proj writes, final reads

    // mask -> transposed u8 [b][n][q]
    mask_transpose<<<dim3(NB, NQn / 64, NNn / 64), 256, 0, stream>>>(mask, maskT8);
    // K,V projections (dual-pass over shared X tile)
    proj_kernel<<<dim3(NB * NNn / 64, 2), 256, 0, stream>>>(
        enc_nodes, Wk, Wv, nullptr, nullptr, nullptr, Kbuf, Vbuf);
    // Q projection (concat attr handled as rank-1 term with Wq row 128)
    proj_kernel<<<dim3(NB * NQn / 64, 2), 256, 0, stream>>>(
        enc_last, Wq, nullptr, Wq + 128 * 128, attr, nullptr, Qbuf, nullptr);
    // masked multi-head attention: 2q/lane, 4 node-splits, 4 waves/SIMD
    attn_kernel<<<dim3(NB, 2, 4), 512, 0, stream>>>(
        Qbuf, Kbuf, Vbuf, maskT8, ATT, P1, P2, P3, L0, L1, L2, L3);
    // merge node-splits (P0 aliases ATT)
    attn_merge<<<dim3(NB * NQn * 32 / 256), 256, 0, stream>>>(
        ATT, P1, P2, P3, L0, L1, L2, L3, Vbuf, ATT);
    // combine projection + bias (MH aliases dead Qbuf)
    proj_kernel<<<dim3(NB * NQn / 64, 2), 256, 0, stream>>>(
        ATT, Wcomb, nullptr, nullptr, nullptr, bcomb, MH, nullptr);
    // compatibility score + tanh clip + masked softmax
    final_kernel<<<dim3(NB * NQn / 64), 512, 0, stream>>>(
        MH, enc_nodes, mask, out);
}